// Round 7
// baseline (435.895 us; speedup 1.0000x reference)
//
#include <hip/hip_runtime.h>
#include <stdint.h>

#define NB 32
#define NT 2000
#define NH 256
#define NS 63
#define LDSROW 264                 // padded bf16 row stride (528 B)
#define TILE_USH (65 * LDSROW)     // one E/h region: 17160 ushorts = 34320 B
#define NTILES 4                   // tiles per persistent block
#define TBX 8                      // 8 * 4 * 63 = 2016 >= 2000

typedef __attribute__((ext_vector_type(8))) short bf16x8;
typedef __attribute__((ext_vector_type(4))) float f32x4;

__device__ inline unsigned short f2bf(float f) {
  union { float f; uint32_t u; } v; v.f = f;
  return (unsigned short)((v.u + 0x7fffu + ((v.u >> 16) & 1u)) >> 16);  // RNE
}
__device__ inline unsigned int pk2(float a, float b) {
  return (unsigned int)f2bf(a) | ((unsigned int)f2bf(b) << 16);
}
__device__ inline bf16x8 pack8(const float* g) {
  union { bf16x8 v; unsigned int u[4]; } c;
  c.u[0] = pk2(g[0], g[1]); c.u[1] = pk2(g[2], g[3]);
  c.u[2] = pk2(g[4], g[5]); c.u[3] = pk2(g[6], g[7]);
  return c.v;
}
// HW packed f32->bf16 (RNE, identical to f2bf for normal values).
__device__ inline unsigned int pk2_hw(float a, float b) {
  unsigned int r;
  asm("v_cvt_pk_bf16_f32 %0, %1, %2" : "=v"(r) : "v"(a), "v"(b));
  return r;
}
__device__ inline unsigned short cvt1_hw(float a) {
  unsigned int r;
  asm("v_cvt_pk_bf16_f32 %0, %1, %1" : "=v"(r) : "v"(a));
  return (unsigned short)r;
}

// Pre-packed MFMA B-fragment layouts (bf16), built once per launch in d_ws:
//   W1F: [km:16][c:4][tn:4][lane:64][j:8]  -> 16384 slots * 16 B = 256 KiB
//   W2F: [ks:8][tn:4][lane:64][j:8]        ->  2048 slots * 16 B =  32 KiB
#define NSLOT1 (16 * 4 * 4 * 64)
#define NSLOT2 (8 * 4 * 64)
#define WS_NEEDED ((size_t)(NSLOT1 + NSLOT2) * 16)

__global__ __launch_bounds__(256) void prep_weights(
    const float* __restrict__ W1, const float* __restrict__ W2,
    unsigned short* __restrict__ w1f, unsigned short* __restrict__ w2f) {
  const int tid = blockIdx.x * 256 + threadIdx.x;
  if (tid < NSLOT1) {
    const int lane = tid & 63;
    const int quad = lane >> 4, l16 = lane & 15;
    int r = tid >> 6;
    const int tn = r & 3; r >>= 2;
    const int wv = r & 3; r >>= 2;
    const int km = r;  // 0..15
    const int kb = (km >> 3) * 256 + (km & 7) * 32 + quad * 8;
    const int n = wv * 64 + tn * 16 + l16;
    ushort4 lo, hi;
    lo.x = f2bf(W1[(size_t)(kb + 0) * NH + n]);
    lo.y = f2bf(W1[(size_t)(kb + 1) * NH + n]);
    lo.z = f2bf(W1[(size_t)(kb + 2) * NH + n]);
    lo.w = f2bf(W1[(size_t)(kb + 3) * NH + n]);
    hi.x = f2bf(W1[(size_t)(kb + 4) * NH + n]);
    hi.y = f2bf(W1[(size_t)(kb + 5) * NH + n]);
    hi.z = f2bf(W1[(size_t)(kb + 6) * NH + n]);
    hi.w = f2bf(W1[(size_t)(kb + 7) * NH + n]);
    *(ushort4*)&w1f[(size_t)tid * 8] = lo;
    *(ushort4*)&w1f[(size_t)tid * 8 + 4] = hi;
  } else if (tid < NSLOT1 + NSLOT2) {
    const int t2 = tid - NSLOT1;
    const int lane = t2 & 63;
    const int quad = lane >> 4, l16 = lane & 15;
    const int tn = (t2 >> 6) & 3;
    const int ks = t2 >> 8;  // 0..7
    const int kb = ks * 32 + quad * 8;
    const int n = tn * 16 + l16;
    ushort4 lo = {0, 0, 0, 0}, hi = {0, 0, 0, 0};
    if (n < NS) {
      lo.x = f2bf(W2[(size_t)(kb + 0) * NS + n]);
      lo.y = f2bf(W2[(size_t)(kb + 1) * NS + n]);
      lo.z = f2bf(W2[(size_t)(kb + 2) * NS + n]);
      lo.w = f2bf(W2[(size_t)(kb + 3) * NS + n]);
      hi.x = f2bf(W2[(size_t)(kb + 4) * NS + n]);
      hi.y = f2bf(W2[(size_t)(kb + 5) * NS + n]);
      hi.z = f2bf(W2[(size_t)(kb + 6) * NS + n]);
      hi.w = f2bf(W2[(size_t)(kb + 7) * NS + n]);
    }
    *(ushort4*)&w2f[(size_t)t2 * 8] = lo;
    *(ushort4*)&w2f[(size_t)t2 * 8 + 4] = hi;
  }
}

// ---- helpers ----

// Issue E loads for a tile into registers (4 rows/wave + boundary row, wave0).
__device__ __forceinline__ void issueE(const float* __restrict__ Eb, int base,
                                       int w, int lane, int tid,
                                       float4 eb[4], float4& eb4) {
  #pragma unroll
  for (int it = 0; it < 4; ++it) {
    int tr = base + it * 16 + w;
    tr = (tr < 0) ? 0 : (tr > NT - 1 ? NT - 1 : tr);
    eb[it] = *(const float4*)&Eb[(size_t)tr * NH + (lane << 2)];
  }
  if (tid < 64) {
    int tr = base + 64; if (tr > NT - 1) tr = NT - 1;
    eb4 = *(const float4*)&Eb[(size_t)tr * NH + (lane << 2)];
  }
}
// Convert held rows and store into region R.
__device__ __forceinline__ void writeE(unsigned short* R, int w, int lane,
                                       int tid, const float4 eb[4],
                                       const float4& eb4) {
  #pragma unroll
  for (int it = 0; it < 4; ++it) {
    const int row = it * 16 + w;
    uint2 o; o.x = pk2_hw(eb[it].x, eb[it].y); o.y = pk2_hw(eb[it].z, eb[it].w);
    *(uint2*)&R[row * LDSROW + (lane << 2)] = o;
  }
  if (tid < 64) {
    uint2 o; o.x = pk2_hw(eb4.x, eb4.y); o.y = pk2_hw(eb4.z, eb4.w);
    *(uint2*)&R[64 * LDSROW + (lane << 2)] = o;
  }
}

// R7: persistent 1024-thread block (16 waves), 256 blocks = 1/CU, 4 tiles
// each. Wave (rq = w>>2, c = w&3): GEMM1 rows rq*16..+15, cols c*64..+63 ->
// acc[1][4] = 16 AGPR only, freeing VGPRs for cross-tile E prefetch.
// Double-buffered E/h regions + separate U array (86 KB dynamic LDS).
// 3 barriers/tile; E(k+1) loads issued one tile early (HBM off critical path).
template <bool PACKED>
__global__ __launch_bounds__(1024, 4) void fused_kernel(
    const float* __restrict__ E, const float* __restrict__ logits,
    const int* __restrict__ kw,
    const float* __restrict__ W1, const float* __restrict__ W2,
    const unsigned short* __restrict__ w1f, const unsigned short* __restrict__ w2f,
    const float* __restrict__ b1, const float* __restrict__ b2,
    float* __restrict__ out) {
  const int b = blockIdx.y;
  const int bx = blockIdx.x;
  const int tid = threadIdx.x;
  const int w = tid >> 6;      // 0..15
  const int lane = tid & 63;
  const int quad = lane >> 4;
  const int l16 = lane & 15;
  const int c = w & 3;         // col-slice
  const int rq = w >> 2;       // row-quarter
  const int n0 = c * 64;

  extern __shared__ unsigned short lds[];
  unsigned short* rgn0 = lds;
  unsigned short* rgn1 = lds + TILE_USH;
  float* U = (float*)(lds + 2 * TILE_USH);   // [64][68] f32, separate area

  const float* Eb = E + (size_t)b * NT * NH;
  const float* lb = logits + (size_t)b * NT * NS;

  // ---- prologue: stage tile 0 directly into rgn0 ----
  {
    const int base = bx * (NTILES * 63) - 1;
    #pragma unroll
    for (int it = 0; it < 4; ++it) {
      const int row = it * 16 + w;
      int tr = base + row;
      tr = (tr < 0) ? 0 : (tr > NT - 1 ? NT - 1 : tr);
      float4 v = *(const float4*)&Eb[(size_t)tr * NH + (lane << 2)];
      uint2 o; o.x = pk2_hw(v.x, v.y); o.y = pk2_hw(v.z, v.w);
      *(uint2*)&rgn0[row * LDSROW + (lane << 2)] = o;
    }
    if (tid < 64) {
      int tr = base + 64; if (tr > NT - 1) tr = NT - 1;
      float4 v = *(const float4*)&Eb[(size_t)tr * NH + (lane << 2)];
      uint2 o; o.x = pk2_hw(v.x, v.y); o.y = pk2_hw(v.z, v.w);
      *(uint2*)&rgn0[64 * LDSROW + (lane << 2)] = o;
    }
  }
  // issue E loads for tile 1 (land during tile 0's GEMM1)
  float4 eb[4]; float4 eb4;
  issueE(Eb, (bx * NTILES + 1) * 63 - 1, w, lane, tid, eb, eb4);
  __syncthreads();

  for (int k = 0; k < NTILES; ++k) {
    const int a0 = (bx * NTILES + k) * 63;
    unsigned short* Rc = (k & 1) ? rgn1 : rgn0;
    unsigned short* Rn = (k & 1) ? rgn0 : rgn1;

    // ---- phase 1: GEMM1 (rows rq*16..+15, cols n0..n0+63) ----
    f32x4 acc[4];
    #pragma unroll
    for (int tn = 0; tn < 4; ++tn) acc[tn] = (f32x4){0.f, 0.f, 0.f, 0.f};

    if constexpr (PACKED) {
      const unsigned short* wbase = w1f + (size_t)(((c << 2) * 64) + lane) * 8;
#define W1F_AT(KM, TN) \
  (*(const bf16x8*)(wbase + ((size_t)((((KM) << 4) + (TN))) << 9)))
      bf16x8 cb0 = W1F_AT(0, 0), cb1 = W1F_AT(0, 1);
      bf16x8 cb2 = W1F_AT(0, 2), cb3 = W1F_AT(0, 3);
      #pragma unroll
      for (int km = 0; km < 16; ++km) {
        bf16x8 nb0, nb1, nb2, nb3;
        if (km < 15) {  // one-ahead register double buffer
          nb0 = W1F_AT(km + 1, 0); nb1 = W1F_AT(km + 1, 1);
          nb2 = W1F_AT(km + 1, 2); nb3 = W1F_AT(km + 1, 3);
        }
        const int aoff = (km >> 3) ? 0 : 1;  // top half pairs e[t+1]
        bf16x8 af = *(const bf16x8*)&Rc[(rq * 16 + l16 + aoff) * LDSROW +
                                        (km & 7) * 32 + quad * 8];
        acc[0] = __builtin_amdgcn_mfma_f32_16x16x32_bf16(af, cb0, acc[0], 0, 0, 0);
        acc[1] = __builtin_amdgcn_mfma_f32_16x16x32_bf16(af, cb1, acc[1], 0, 0, 0);
        acc[2] = __builtin_amdgcn_mfma_f32_16x16x32_bf16(af, cb2, acc[2], 0, 0, 0);
        acc[3] = __builtin_amdgcn_mfma_f32_16x16x32_bf16(af, cb3, acc[3], 0, 0, 0);
        if (km < 15) { cb0 = nb0; cb1 = nb1; cb2 = nb2; cb3 = nb3; }
      }
#undef W1F_AT
    } else {
      const float* w1p = W1 + (size_t)(quad * 8) * NH + n0 + l16;
      #pragma unroll
      for (int km = 0; km < 16; ++km) {
        const int hk = (km >> 3) * 256 + (km & 7) * 32;
        const int aoff = (km >> 3) ? 0 : 1;
        bf16x8 af = *(const bf16x8*)&Rc[(rq * 16 + l16 + aoff) * LDSROW +
                                        (km & 7) * 32 + quad * 8];
        float g[8], gn[8];
        #pragma unroll
        for (int j = 0; j < 8; ++j) g[j] = w1p[(size_t)(hk + j) * NH];
        #pragma unroll
        for (int tn = 0; tn < 4; ++tn) {
          if (tn < 3) {
            #pragma unroll
            for (int j = 0; j < 8; ++j)
              gn[j] = w1p[(size_t)(hk + j) * NH + (tn + 1) * 16];
          }
          bf16x8 bq = pack8(g);
          acc[tn] = __builtin_amdgcn_mfma_f32_16x16x32_bf16(af, bq, acc[tn], 0, 0, 0);
          if (tn < 3) {
            #pragma unroll
            for (int j = 0; j < 8; ++j) g[j] = gn[j];
          }
        }
      }
    }
    __syncthreads();  // GEMM1 A-reads done

    // ---- phase 2: write E(k+1) -> Rn ; h -> Rc ----
    if (k < NTILES - 1) writeE(Rn, w, lane, tid, eb, eb4);
    #pragma unroll
    for (int tn = 0; tn < 4; ++tn) {
      float b1v = b1[n0 + tn * 16 + l16];
      #pragma unroll
      for (int r = 0; r < 4; ++r) {
        float hv = fmaxf(acc[tn][r] + b1v, 0.f);
        Rc[(rq * 16 + quad * 4 + r) * LDSROW + n0 + tn * 16 + l16] = cvt1_hw(hv);
      }
    }
    __syncthreads();

    // ---- phase 3: GEMM2 + write_U (waves 0..3 only; U is separate) ----
    if (w < 4) {
      const int m0 = w * 16;
      float lpv[16];
      #pragma unroll
      for (int tn = 0; tn < 4; ++tn) {
        const int s = tn * 16 + l16;
        const int cc = (s < NS) ? s : NS - 1;
        #pragma unroll
        for (int r = 0; r < 4; ++r) {
          int tt = a0 + m0 + quad * 4 + r;
          if (tt > NT - 1) tt = NT - 1;
          lpv[tn * 4 + r] = lb[(size_t)tt * NS + cc];
        }
      }
      f32x4 acc2[4];
      #pragma unroll
      for (int tn = 0; tn < 4; ++tn) acc2[tn] = (f32x4){0.f, 0.f, 0.f, 0.f};

      if constexpr (PACKED) {
        const unsigned short* w2base = w2f + (size_t)lane * 8;
        #pragma unroll
        for (int ks = 0; ks < 8; ++ks) {
          bf16x8 af = *(const bf16x8*)&Rc[(m0 + l16) * LDSROW + ks * 32 + quad * 8];
          #pragma unroll
          for (int tn = 0; tn < 4; ++tn) {
            bf16x8 bq = *(const bf16x8*)(w2base + ((size_t)((ks << 2) + tn) << 9));
            acc2[tn] = __builtin_amdgcn_mfma_f32_16x16x32_bf16(af, bq, acc2[tn], 0, 0, 0);
          }
        }
      } else {
        #pragma unroll
        for (int ks = 0; ks < 8; ++ks) {
          const int k0 = ks * 32;
          bf16x8 af = *(const bf16x8*)&Rc[(m0 + l16) * LDSROW + k0 + quad * 8];
          #pragma unroll
          for (int tn = 0; tn < 4; ++tn) {
            const int n = tn * 16 + l16;
            float g[8];
            #pragma unroll
            for (int j = 0; j < 8; ++j)
              g[j] = (n < NS) ? W2[(size_t)(k0 + quad * 8 + j) * NS + n] : 0.f;
            bf16x8 bq = pack8(g);
            acc2[tn] = __builtin_amdgcn_mfma_f32_16x16x32_bf16(af, bq, acc2[tn], 0, 0, 0);
          }
        }
      }
      // U[m][s] = trans + b2 + logits (acc2 is wave-private: no barrier needed)
      #pragma unroll
      for (int tn = 0; tn < 4; ++tn) {
        const int s = tn * 16 + l16;
        const float b2v = (s < NS) ? b2[s] : 0.f;
        #pragma unroll
        for (int r = 0; r < 4; ++r)
          U[(m0 + quad * 4 + r) * 68 + s] = acc2[tn][r] + b2v + lpv[tn * 4 + r];
      }
    }
    __syncthreads();  // U complete; h dead

    // ---- phase 4: issue E(k+2), softmax (4 rows/wave). No trailing barrier:
    // U(k+1) writes and Rn-region reuse are >= 2 barriers downstream. ----
    if (k < NTILES - 2)
      issueE(Eb, (bx * NTILES + k + 2) * 63 - 1, w, lane, tid, eb, eb4);

    #pragma unroll
    for (int rr = 0; rr < 4; ++rr) {
      const int j = w * 4 + rr;
      const int t = a0 + j;
      if (j == 63 || t > NT - 1) continue;
      float sc;
      if (t == 0) {
        float v = (lane < NS) ? lb[lane] : -1e30f;  // logits row 0
        float m = v;
        #pragma unroll
        for (int o = 32; o > 0; o >>= 1) m = fmaxf(m, __shfl_xor(m, o));
        float ee = (lane < NS) ? __expf(v - m) : 0.f;
        float ss = ee;
        #pragma unroll
        for (int o = 32; o > 0; o >>= 1) ss += __shfl_xor(ss, o);
        const float lse = m + __logf(ss);
        const float f00 = lb[kw[b * 32]] - lse;
        sc = ((lane == 0) ? f00 : 0.f) + U[68 + lane];  // + U[1]
      } else if (t == NT - 1) {
        sc = U[j * 68 + lane];
      } else {
        sc = U[j * 68 + lane] + U[(j + 1) * 68 + lane];
      }
      float e = (lane < NS) ? __expf(sc) : 0.f;
      float s = e;
      #pragma unroll
      for (int o = 32; o > 0; o >>= 1) s += __shfl_xor(s, o);
      const float sinv = __builtin_amdgcn_rcpf(s);
      if (lane < NS) out[((size_t)b * NT + t) * NS + lane] = e * sinv;
    }
  }
}

extern "C" void kernel_launch(void* const* d_in, const int* in_sizes, int n_in,
                              void* d_out, int out_size, void* d_ws, size_t ws_size,
                              hipStream_t stream) {
  const float* logits = (const float*)d_in[0];
  const float* E      = (const float*)d_in[1];
  const int*   kw     = (const int*)d_in[2];
  const float* W1     = (const float*)d_in[3];
  const float* b1     = (const float*)d_in[4];
  const float* W2     = (const float*)d_in[5];
  const float* b2     = (const float*)d_in[6];
  float* out = (float*)d_out;

  dim3 g(TBX, NB);  // 8 x 32 = 256 blocks = 1 per CU, 4 tiles each
  const size_t shmem = (size_t)2 * TILE_USH * sizeof(unsigned short)  // 68640
                     + (size_t)64 * 68 * sizeof(float);               // 17408

  if (ws_size >= WS_NEEDED && d_ws != nullptr) {
    unsigned short* w1f = (unsigned short*)d_ws;
    unsigned short* w2f = w1f + (size_t)NSLOT1 * 8;
    prep_weights<<<dim3((NSLOT1 + NSLOT2) / 256), 256, 0, stream>>>(W1, W2, w1f, w2f);
    fused_kernel<true><<<g, 1024, shmem, stream>>>(E, logits, kw, W1, W2, w1f, w2f,
                                                   b1, b2, out);
  } else {
    fused_kernel<false><<<g, 1024, shmem, stream>>>(E, logits, kw, W1, W2, nullptr,
                                                    nullptr, b1, b2, out);
  }
}

// Round 8
// 134.144 us; speedup vs baseline: 3.2494x; 3.2494x over previous
//
#include <hip/hip_runtime.h>
#include <stdint.h>

#define NB 32
#define NT 2000
#define NH 256
#define NS 63
#define LDSROW 264   // padded bf16 row stride (528 B)

typedef __attribute__((ext_vector_type(8))) short bf16x8;
typedef __attribute__((ext_vector_type(4))) float f32x4;

__device__ inline unsigned short f2bf(float f) {
  union { float f; uint32_t u; } v; v.f = f;
  return (unsigned short)((v.u + 0x7fffu + ((v.u >> 16) & 1u)) >> 16);  // RNE
}
__device__ inline unsigned int pk2(float a, float b) {
  return (unsigned int)f2bf(a) | ((unsigned int)f2bf(b) << 16);
}
__device__ inline bf16x8 pack8(const float* g) {
  union { bf16x8 v; unsigned int u[4]; } c;
  c.u[0] = pk2(g[0], g[1]); c.u[1] = pk2(g[2], g[3]);
  c.u[2] = pk2(g[4], g[5]); c.u[3] = pk2(g[6], g[7]);
  return c.v;
}

// HW packed f32->bf16 (RNE, identical to f2bf for normal values).
__device__ inline unsigned int pk2_hw(float a, float b) {
  unsigned int r;
  asm("v_cvt_pk_bf16_f32 %0, %1, %2" : "=v"(r) : "v"(a), "v"(b));
  return r;
}
__device__ inline unsigned short cvt1_hw(float a) {
  unsigned int r;
  asm("v_cvt_pk_bf16_f32 %0, %1, %1" : "=v"(r) : "v"(a));
  return (unsigned short)r;
}

// Pre-packed MFMA B-fragment layouts (bf16), built once per launch in d_ws:
//   W1F: [km:16][c:4][tn:4][lane:64][j:8]  -> 16384 slots * 16 B = 256 KiB
//   W2F: [ks:8][tn:4][lane:64][j:8]        ->  2048 slots * 16 B =  32 KiB
#define NSLOT1 (16 * 4 * 4 * 64)
#define NSLOT2 (8 * 4 * 64)
#define WS_NEEDED ((size_t)(NSLOT1 + NSLOT2) * 16)

__global__ __launch_bounds__(256) void prep_weights(
    const float* __restrict__ W1, const float* __restrict__ W2,
    unsigned short* __restrict__ w1f, unsigned short* __restrict__ w2f) {
  const int tid = blockIdx.x * 256 + threadIdx.x;
  if (tid < NSLOT1) {
    const int lane = tid & 63;
    const int quad = lane >> 4, l16 = lane & 15;
    int r = tid >> 6;
    const int tn = r & 3; r >>= 2;
    const int wv = r & 3; r >>= 2;
    const int km = r;  // 0..15
    const int kb = (km >> 3) * 256 + (km & 7) * 32 + quad * 8;
    const int n = wv * 64 + tn * 16 + l16;
    ushort4 lo, hi;
    lo.x = f2bf(W1[(size_t)(kb + 0) * NH + n]);
    lo.y = f2bf(W1[(size_t)(kb + 1) * NH + n]);
    lo.z = f2bf(W1[(size_t)(kb + 2) * NH + n]);
    lo.w = f2bf(W1[(size_t)(kb + 3) * NH + n]);
    hi.x = f2bf(W1[(size_t)(kb + 4) * NH + n]);
    hi.y = f2bf(W1[(size_t)(kb + 5) * NH + n]);
    hi.z = f2bf(W1[(size_t)(kb + 6) * NH + n]);
    hi.w = f2bf(W1[(size_t)(kb + 7) * NH + n]);
    *(ushort4*)&w1f[(size_t)tid * 8] = lo;
    *(ushort4*)&w1f[(size_t)tid * 8 + 4] = hi;
  } else if (tid < NSLOT1 + NSLOT2) {
    const int t2 = tid - NSLOT1;
    const int lane = t2 & 63;
    const int quad = lane >> 4, l16 = lane & 15;
    const int tn = (t2 >> 6) & 3;
    const int ks = t2 >> 8;  // 0..7
    const int kb = ks * 32 + quad * 8;
    const int n = tn * 16 + l16;
    ushort4 lo = {0, 0, 0, 0}, hi = {0, 0, 0, 0};
    if (n < NS) {
      lo.x = f2bf(W2[(size_t)(kb + 0) * NS + n]);
      lo.y = f2bf(W2[(size_t)(kb + 1) * NS + n]);
      lo.z = f2bf(W2[(size_t)(kb + 2) * NS + n]);
      lo.w = f2bf(W2[(size_t)(kb + 3) * NS + n]);
      hi.x = f2bf(W2[(size_t)(kb + 4) * NS + n]);
      hi.y = f2bf(W2[(size_t)(kb + 5) * NS + n]);
      hi.z = f2bf(W2[(size_t)(kb + 6) * NS + n]);
      hi.w = f2bf(W2[(size_t)(kb + 7) * NS + n]);
    }
    *(ushort4*)&w2f[(size_t)t2 * 8] = lo;
    *(ushort4*)&w2f[(size_t)t2 * 8 + 4] = hi;
  }
}

// R8 = R4 (proven 42.3 us/dispatch structure: 256 threads, 64-row tile,
// 4 blocks/CU, 64 VGPR + 64 AGPR) + two register-neutral tweaks:
//  (1) s_setprio(1) around the GEMM1/GEMM2 MFMA clusters (T5) — the 4
//      resident blocks/CU sit at different phases, so MFMA-phase waves win
//      SIMD arbitration over stage/softmax-phase waves.
//  (2) softmax fully unrolled + 16-row batched: 16 independent shfl-xor
//      reduction chains interleaved per butterfly level (was a runtime loop
//      of serial 6-deep chains). ev/sm live only after AGPRs are dead.
template <bool PACKED>
__global__ __launch_bounds__(256, 4) void fused_kernel(
    const float* __restrict__ E, const float* __restrict__ logits,
    const int* __restrict__ kw,
    const float* __restrict__ W1, const float* __restrict__ W2,
    const unsigned short* __restrict__ w1f, const unsigned short* __restrict__ w2f,
    const float* __restrict__ b1, const float* __restrict__ b2,
    float* __restrict__ out) {
  const int b = blockIdx.y;
  const int a0 = blockIdx.x * 63;   // first align t of this block
  const int base = a0 - 1;          // first trans row computed
  const int tid = threadIdx.x;
  const int w = tid >> 6;
  const int lane = tid & 63;
  const int quad = lane >> 4;
  const int l16 = lane & 15;
  const int n0 = w * 64;

  __shared__ unsigned short lds[65 * LDSROW];  // 34320 B: E-tile -> h -> U
  float* TRf = (float*)lds;                    // U[64][68] f32 (17408 B)

  const float* Eb = E + (size_t)b * NT * NH;
  const float* lb = logits + (size_t)b * NT * NS;

  // Stage E rows base..base+64 (clamped), f32 -> bf16 via v_cvt_pk.
  #pragma unroll
  for (int it = 0; it < 16; ++it) {
    const int row = it * 4 + w;
    int tr = base + row;
    tr = (tr < 0) ? 0 : (tr > NT - 1 ? NT - 1 : tr);
    float4 v = *(const float4*)&Eb[(size_t)tr * NH + (lane << 2)];
    uint2 o;
    o.x = pk2_hw(v.x, v.y); o.y = pk2_hw(v.z, v.w);
    *(uint2*)&lds[row * LDSROW + (lane << 2)] = o;
  }
  if (tid < 64) {
    int tr = base + 64; if (tr > NT - 1) tr = NT - 1;
    float4 v = *(const float4*)&Eb[(size_t)tr * NH + (lane << 2)];
    uint2 o;
    o.x = pk2_hw(v.x, v.y); o.y = pk2_hw(v.z, v.w);
    *(uint2*)&lds[64 * LDSROW + (lane << 2)] = o;
  }
  __syncthreads();

  // GEMM1: h[m][n] = e[base+m+1]@W1_top + e[base+m]@W1_bot  (m = 0..63,
  // wave w owns cols n0..n0+63)
  f32x4 acc[4][4];
  #pragma unroll
  for (int tm = 0; tm < 4; ++tm)
    #pragma unroll
    for (int tn = 0; tn < 4; ++tn) acc[tm][tn] = (f32x4){0.f, 0.f, 0.f, 0.f};

  if constexpr (PACKED) {
    // fragment (km,tn) lives at wbase + ((km<<4)+tn)*512 ushorts
    const unsigned short* wbase = w1f + (size_t)(((w << 2) * 64) + lane) * 8;
#define W1F_AT(KM, TN) \
  (*(const bf16x8*)(wbase + ((size_t)((((KM) << 4) + (TN))) << 9)))
    bf16x8 cb0 = W1F_AT(0, 0), cb1 = W1F_AT(0, 1);
    bf16x8 cb2 = W1F_AT(0, 2), cb3 = W1F_AT(0, 3);
    __builtin_amdgcn_s_setprio(1);  // T5: favor MFMA-phase wave on this SIMD
    #pragma unroll
    for (int km = 0; km < 16; ++km) {
      bf16x8 nb0, nb1, nb2, nb3;
      if (km < 15) {  // one-ahead register double buffer (hides L2 latency)
        nb0 = W1F_AT(km + 1, 0); nb1 = W1F_AT(km + 1, 1);
        nb2 = W1F_AT(km + 1, 2); nb3 = W1F_AT(km + 1, 3);
      }
      const int aoff = (km >> 3) ? 0 : 1;  // top half pairs e[t+1]
      bf16x8 af[4];
      #pragma unroll
      for (int tm = 0; tm < 4; ++tm)
        af[tm] = *(const bf16x8*)&lds[(tm * 16 + l16 + aoff) * LDSROW +
                                      (km & 7) * 32 + quad * 8];
      #pragma unroll
      for (int tm = 0; tm < 4; ++tm)
        acc[tm][0] = __builtin_amdgcn_mfma_f32_16x16x32_bf16(af[tm], cb0, acc[tm][0], 0, 0, 0);
      #pragma unroll
      for (int tm = 0; tm < 4; ++tm)
        acc[tm][1] = __builtin_amdgcn_mfma_f32_16x16x32_bf16(af[tm], cb1, acc[tm][1], 0, 0, 0);
      #pragma unroll
      for (int tm = 0; tm < 4; ++tm)
        acc[tm][2] = __builtin_amdgcn_mfma_f32_16x16x32_bf16(af[tm], cb2, acc[tm][2], 0, 0, 0);
      #pragma unroll
      for (int tm = 0; tm < 4; ++tm)
        acc[tm][3] = __builtin_amdgcn_mfma_f32_16x16x32_bf16(af[tm], cb3, acc[tm][3], 0, 0, 0);
      if (km < 15) { cb0 = nb0; cb1 = nb1; cb2 = nb2; cb3 = nb3; }
    }
    __builtin_amdgcn_s_setprio(0);
#undef W1F_AT
  } else {
    const float* w1p = W1 + (size_t)(quad * 8) * NH + n0 + l16;
    #pragma unroll
    for (int km = 0; km < 16; ++km) {
      const int hk = (km >> 3) * 256 + (km & 7) * 32;
      const int aoff = (km >> 3) ? 0 : 1;
      bf16x8 af[4];
      #pragma unroll
      for (int tm = 0; tm < 4; ++tm)
        af[tm] = *(const bf16x8*)&lds[(tm * 16 + l16 + aoff) * LDSROW +
                                      (km & 7) * 32 + quad * 8];
      float g[8], gn[8];
      #pragma unroll
      for (int j = 0; j < 8; ++j) g[j] = w1p[(size_t)(hk + j) * NH];
      #pragma unroll
      for (int tn = 0; tn < 4; ++tn) {
        if (tn < 3) {
          #pragma unroll
          for (int j = 0; j < 8; ++j)
            gn[j] = w1p[(size_t)(hk + j) * NH + (tn + 1) * 16];
        }
        bf16x8 bq = pack8(g);
        #pragma unroll
        for (int tm = 0; tm < 4; ++tm)
          acc[tm][tn] = __builtin_amdgcn_mfma_f32_16x16x32_bf16(
              af[tm], bq, acc[tm][tn], 0, 0, 0);
        if (tn < 3) {
          #pragma unroll
          for (int j = 0; j < 8; ++j) g[j] = gn[j];
        }
      }
    }
  }
  __syncthreads();  // GEMM1 A-reads done

  // h = relu(acc + b1) -> bf16 LDS rows 0..63 (HW cvt, 1 op/value)
  #pragma unroll
  for (int tn = 0; tn < 4; ++tn) {
    float b1v = b1[n0 + tn * 16 + l16];
    #pragma unroll
    for (int tm = 0; tm < 4; ++tm)
      #pragma unroll
      for (int r = 0; r < 4; ++r) {
        float hv = fmaxf(acc[tm][tn][r] + b1v, 0.f);
        lds[(tm * 16 + quad * 4 + r) * LDSROW + n0 + tn * 16 + l16] = cvt1_hw(hv);
      }
  }
  __syncthreads();

  // Prefetch logits values for this wave's U rows into registers (latency
  // hides under GEMM2). lpv[tn*4+r] pairs with acc2[tn][r].
  const int m0 = w * 16;
  float lpv[16];
  #pragma unroll
  for (int tn = 0; tn < 4; ++tn) {
    const int s = tn * 16 + l16;
    const int cc = (s < NS) ? s : NS - 1;
    #pragma unroll
    for (int r = 0; r < 4; ++r) {
      int tt = a0 + m0 + quad * 4 + r;
      if (tt > NT - 1) tt = NT - 1;
      lpv[tn * 4 + r] = lb[(size_t)tt * NS + cc];
    }
  }

  // GEMM2: wave w -> trans rows m0..m0+15
  f32x4 acc2[4];
  #pragma unroll
  for (int tn = 0; tn < 4; ++tn) acc2[tn] = (f32x4){0.f, 0.f, 0.f, 0.f};

  if constexpr (PACKED) {
    const unsigned short* w2base = w2f + (size_t)lane * 8;
    __builtin_amdgcn_s_setprio(1);
    #pragma unroll
    for (int ks = 0; ks < 8; ++ks) {
      bf16x8 af = *(const bf16x8*)&lds[(m0 + l16) * LDSROW + ks * 32 + quad * 8];
      #pragma unroll
      for (int tn = 0; tn < 4; ++tn) {
        bf16x8 bq = *(const bf16x8*)(w2base + ((size_t)((ks << 2) + tn) << 9));
        acc2[tn] = __builtin_amdgcn_mfma_f32_16x16x32_bf16(af, bq, acc2[tn], 0, 0, 0);
      }
    }
    __builtin_amdgcn_s_setprio(0);
  } else {
    #pragma unroll
    for (int ks = 0; ks < 8; ++ks) {
      const int k0 = ks * 32;
      bf16x8 af = *(const bf16x8*)&lds[(m0 + l16) * LDSROW + k0 + quad * 8];
      #pragma unroll
      for (int tn = 0; tn < 4; ++tn) {
        const int n = tn * 16 + l16;
        float g[8];
        #pragma unroll
        for (int j = 0; j < 8; ++j)
          g[j] = (n < NS) ? W2[(size_t)(k0 + quad * 8 + j) * NS + n] : 0.f;
        bf16x8 bq = pack8(g);
        acc2[tn] = __builtin_amdgcn_mfma_f32_16x16x32_bf16(af, bq, acc2[tn], 0, 0, 0);
      }
    }
  }
  __syncthreads();  // all h reads done; h region now reused for U

  // U[m][s] = trans[base+m][s] + b2[s] + logp-raw[a0+m][s]  (f32)
  #pragma unroll
  for (int tn = 0; tn < 4; ++tn) {
    const int s = tn * 16 + l16;
    const float b2v = (s < NS) ? b2[s] : 0.f;
    #pragma unroll
    for (int r = 0; r < 4; ++r)
      TRf[(m0 + quad * 4 + r) * 68 + s] = acc2[tn][r] + b2v + lpv[tn * 4 + r];
  }
  __syncthreads();

  // Softmax, fully unrolled + batched: 16 rows/wave, 16 independent
  // shfl-xor reduction chains interleaved per butterfly level.
  // t == 0 (block x==0, wave 0) handled as a scalar special case first.
  if (a0 == 0 && w == 0) {
    float v = (lane < NS) ? lb[lane] : -1e30f;  // logits row 0 from global
    float m = v;
    #pragma unroll
    for (int o = 32; o > 0; o >>= 1) m = fmaxf(m, __shfl_xor(m, o));
    float ee = (lane < NS) ? __expf(v - m) : 0.f;
    float ss = ee;
    #pragma unroll
    for (int o = 32; o > 0; o >>= 1) ss += __shfl_xor(ss, o);
    const float lse = m + __logf(ss);
    const float f00 = lb[kw[b * 32]] - lse;
    float sc = ((lane == 0) ? f00 : 0.f) + TRf[68 + lane];  // + U[1]
    float e = (lane < NS) ? __expf(sc) : 0.f;
    float s = e;
    #pragma unroll
    for (int o = 32; o > 0; o >>= 1) s += __shfl_xor(s, o);
    if (lane < NS)
      out[(size_t)b * NT * NS + lane] = e * __builtin_amdgcn_rcpf(s);
  }

  float ev[16], sm[16];
  #pragma unroll
  for (int rr = 0; rr < 16; ++rr) {
    const int j = m0 + rr;
    const int t = a0 + j;
    const bool valid = (j < 63) && (t < NT) && (t != 0);
    float u0 = valid ? TRf[j * 68 + lane] : 0.f;
    float u1 = (valid && t != NT - 1) ? TRf[(j + 1) * 68 + lane] : 0.f;
    ev[rr] = (valid && lane < NS) ? __expf(u0 + u1) : 0.f;
    sm[rr] = ev[rr];
  }
  #pragma unroll
  for (int o = 32; o > 0; o >>= 1) {
    #pragma unroll
    for (int rr = 0; rr < 16; ++rr) sm[rr] += __shfl_xor(sm[rr], o);
  }
  #pragma unroll
  for (int rr = 0; rr < 16; ++rr) {
    const int j = m0 + rr;
    const int t = a0 + j;
    const bool valid = (j < 63) && (t < NT) && (t != 0);
    if (valid && lane < NS)
      out[((size_t)b * NT + t) * NS + lane] = ev[rr] * __builtin_amdgcn_rcpf(sm[rr]);
  }
}

extern "C" void kernel_launch(void* const* d_in, const int* in_sizes, int n_in,
                              void* d_out, int out_size, void* d_ws, size_t ws_size,
                              hipStream_t stream) {
  const float* logits = (const float*)d_in[0];
  const float* E      = (const float*)d_in[1];
  const int*   kw     = (const int*)d_in[2];
  const float* W1     = (const float*)d_in[3];
  const float* b1     = (const float*)d_in[4];
  const float* W2     = (const float*)d_in[5];
  const float* b2     = (const float*)d_in[6];
  float* out = (float*)d_out;

  dim3 g(32, NB);  // 32 t-blocks (63 t's each) x 32 batches = 1024 blocks

  if (ws_size >= WS_NEEDED && d_ws != nullptr) {
    unsigned short* w1f = (unsigned short*)d_ws;
    unsigned short* w2f = w1f + (size_t)NSLOT1 * 8;
    prep_weights<<<dim3((NSLOT1 + NSLOT2) / 256), 256, 0, stream>>>(W1, W2, w1f, w2f);
    fused_kernel<true><<<g, 256, 0, stream>>>(E, logits, kw, W1, W2, w1f, w2f,
                                              b1, b2, out);
  } else {
    fused_kernel<false><<<g, 256, 0, stream>>>(E, logits, kw, W1, W2, nullptr,
                                               nullptr, b1, b2, out);
  }
}